// Round 1
// baseline (662.917 us; speedup 1.0000x reference)
//
#include <hip/hip_runtime.h>
#include <cstdint>
#include <cstddef>

typedef _Float16 f16;
typedef _Float16 half8 __attribute__((ext_vector_type(8)));
typedef float f32x4 __attribute__((ext_vector_type(4)));

#define BN_EPS 1e-5f

// ---------------- workspace layout (bytes) ----------------
// xb  : f16 [64][32][32][256]  NHWC search        33,554,432
// zb  : f16 [64][16][16][256]  NHWC template       8,388,608
// wxA : f16 [9][256cout][256cin]                   1,179,648
// wzA : f16 [9][256cout][256cin]                   1,179,648
// bnx : f32 scale[256], bias[256]                      2,048
// bnz : f32 scale[256], bias[256]                      2,048
// xf  : f32 [64][256][30][30]                     58,982,400
// zf  : f32 [64][256][14][14]                     12,845,056
static constexpr size_t OFF_XB  = 0;
static constexpr size_t OFF_ZB  = 33554432;
static constexpr size_t OFF_WX  = 41943040;
static constexpr size_t OFF_WZ  = 43122688;
static constexpr size_t OFF_BNX = 44302336;
static constexpr size_t OFF_BNZ = 44304384;
static constexpr size_t OFF_XF  = 44306432;
static constexpr size_t OFF_ZF  = 103288832;

// ---------------- NCHW fp32 -> NHWC f16 transpose ----------------
// block handles (b, h, c0..c0+63) for all W; LDS tile breaks the
// transpose so both global read and write are coalesced.
template <int H, int W>
__global__ __launch_bounds__(256) void nchw_to_nhwc_f16(
    const float* __restrict__ src, f16* __restrict__ dst) {
  __shared__ float tile[64][W + 1];  // +1 pad: store-phase reads stride W+1 (odd) -> conflict-free
  const int bid = blockIdx.x;
  const int c0 = (bid & 3) << 6;      // 4 channel-tiles of 64
  const int h = (bid >> 2) % H;
  const int b = bid / (4 * H);
  const float* sp = src + ((b * 256 + c0) * H + h) * W;
  for (int i = threadIdx.x; i < 64 * W; i += 256) {
    int cl = i / W, w = i - cl * W;            // w consecutive -> coalesced read
    tile[cl][w] = sp[cl * (H * W) + w];
  }
  __syncthreads();
  f16* dp = dst + (b * H + h) * W * 256 + c0;
  for (int i = threadIdx.x; i < 64 * W; i += 256) {
    int w = i >> 6, cl = i & 63;               // cl consecutive -> coalesced write
    dp[w * 256 + cl] = (f16)tile[cl][w];
  }
}

// ---------------- weight repack: OIHW fp32 -> [khw][cout][cin] f16 ----------------
__global__ __launch_bounds__(256) void prep_w(const float* __restrict__ w,
                                              f16* __restrict__ wA) {
  int idx = blockIdx.x * 256 + threadIdx.x;    // < 9*256*256
  int cin = idx & 255;
  int cout = (idx >> 8) & 255;
  int khw = idx >> 16;
  wA[idx] = (f16)w[(cout * 256 + cin) * 9 + khw];
}

// ---------------- BN fold: scale = g/sqrt(v+eps), bias = b - m*scale ----------------
__global__ void prep_bn(const float* __restrict__ gamma, const float* __restrict__ beta,
                        const float* __restrict__ mean, const float* __restrict__ var,
                        float* __restrict__ bnout) {
  int c = threadIdx.x;
  float inv = gamma[c] / sqrtf(var[c] + BN_EPS);
  bnout[c] = inv;
  bnout[256 + c] = beta[c] - mean[c] * inv;
}

// ---------------- fused implicit-im2col conv3x3 + BN (MFMA f16) ----------------
// GEMM: C[cout][n=(b,oh,ow)] = sum_k W[cout][k] * im2col[k][n],  k = (khw, cin)
// 128x128 block tile, BK=32, 4 waves each 64x64 (4x4 frags of 16x16x32).
__device__ __forceinline__ void gl_lds16(const f16* g, f16* l) {
  __builtin_amdgcn_global_load_lds((__attribute__((address_space(1))) void*)g,
                                   (__attribute__((address_space(3))) void*)l, 16, 0, 0);
}

template <int HIN, int WIN, int HOUT, int WOUT>
__global__ __launch_bounds__(256) void conv_gemm(
    const f16* __restrict__ inp,   // NHWC f16 [B][HIN][WIN][256]
    const f16* __restrict__ wA,    // [9][256][256]
    const float* __restrict__ bn,  // scale[256], bias[256]
    float* __restrict__ out) {     // NCHW f32 [B][256][HOUT][WOUT]
  constexpr int NPIX = HOUT * WOUT;
  __shared__ f16 As[128 * 32];  // [cout_local][cin32]  rows of 64B, XOR-swizzled chunks
  __shared__ f16 Bs[128 * 32];  // [n_local][cin32]
  const int tid = threadIdx.x;
  const int wid = tid >> 6, lane = tid & 63;
  const int nblk = blockIdx.x, mblk = blockIdx.y;
  const int wm = (wid >> 1) << 6, wn = (wid & 1) << 6;
  const int q = lane >> 4, lm = lane & 15;
  const int sr = lane >> 2, sc = lane & 3;

  // staging rows this lane serves (two 1KB global_load_lds calls per tile per wave)
  const int row0 = (wid << 5) + sr;
  const int row1 = row0 + 16;
  const int swz0 = (sc ^ (row0 & 3)) << 3;  // XOR swizzle of 16B chunks within a row
  const int swz1 = (sc ^ (row1 & 3)) << 3;

  // B rows: decode (b,oh,ow) once; per-k just add (kh*WIN+kw)*256
  int ib0, ib1;
  {
    int n0 = nblk * 128 + row0;
    int b = n0 / NPIX, r = n0 - b * NPIX;
    int oh = r / WOUT, ow = r - oh * WOUT;
    ib0 = ((b * HIN + oh) * WIN + ow) << 8;
    int n1 = n0 + 16;
    b = n1 / NPIX; r = n1 - b * NPIX;
    oh = r / WOUT; ow = r - oh * WOUT;
    ib1 = ((b * HIN + oh) * WIN + ow) << 8;
  }
  const int acol0 = ((mblk << 7) + row0) << 8;
  const int acol1 = ((mblk << 7) + row1) << 8;

  f16* lds_a0 = &As[(wid << 5) * 32];
  f16* lds_a1 = &As[((wid << 5) + 16) * 32];
  f16* lds_b0 = &Bs[(wid << 5) * 32];
  f16* lds_b1 = &Bs[((wid << 5) + 16) * 32];

  f32x4 acc[4][4] = {};
  const int swf = (q ^ (lm & 3)) << 3;  // fragment-read swizzle (undo staging XOR)

  for (int kt = 0; kt < 72; ++kt) {
    const int khw = kt >> 3;
    const int cin0 = (kt & 7) << 5;
    const int kh = khw / 3, kw = khw - kh * 3;
    const int wbase = khw * 65536 + cin0;
    gl_lds16(wA + wbase + acol0 + swz0, lds_a0);
    gl_lds16(wA + wbase + acol1 + swz1, lds_a1);
    const int ioff = ((kh * WIN + kw) << 8) + cin0;
    gl_lds16(inp + ib0 + ioff + swz0, lds_b0);
    gl_lds16(inp + ib1 + ioff + swz1, lds_b1);
    __syncthreads();

    half8 af[4], bf[4];
#pragma unroll
    for (int f = 0; f < 4; ++f) {
      af[f] = *(const half8*)&As[((wm + (f << 4) + lm) << 5) + swf];
      bf[f] = *(const half8*)&Bs[((wn + (f << 4) + lm) << 5) + swf];
    }
#pragma unroll
    for (int fm = 0; fm < 4; ++fm)
#pragma unroll
      for (int fn = 0; fn < 4; ++fn)
        acc[fm][fn] =
            __builtin_amdgcn_mfma_f32_16x16x32_f16(af[fm], bf[fn], acc[fm][fn], 0, 0, 0);
    __syncthreads();
  }

  // epilogue: BN + NCHW store. C/D layout: row m = q*4+reg, col n = lm.
#pragma unroll
  for (int fn = 0; fn < 4; ++fn) {
    int n_g = (nblk << 7) + wn + (fn << 4) + lm;
    int b = n_g / NPIX, r = n_g - b * NPIX;
    int oh = r / WOUT, ow = r - oh * WOUT;
    float* op = out + (b << 8) * (HOUT * WOUT) + oh * WOUT + ow;
#pragma unroll
    for (int fm = 0; fm < 4; ++fm) {
      int m0 = (mblk << 7) + wm + (fm << 4) + (q << 2);
#pragma unroll
      for (int rg = 0; rg < 4; ++rg) {
        int m = m0 + rg;
        op[m * (HOUT * WOUT)] = acc[fm][fn][rg] * bn[m] + bn[256 + m];
      }
    }
  }
}

// ---------------- depthwise xcorr: zf[14x14] over xf[30x30] -> [17x17] ----------------
__global__ __launch_bounds__(256) void xcorr_dw(const float* __restrict__ zf,
                                                const float* __restrict__ xf,
                                                float* __restrict__ out) {
  const int bc = blockIdx.x;  // b*256 + c
  __shared__ float zs[196];
  __shared__ float xs[900];
  const float* zp = zf + bc * 196;
  const float* xp = xf + bc * 900;
  for (int i = threadIdx.x; i < 196; i += 256) zs[i] = zp[i];
  for (int i = threadIdx.x; i < 900; i += 256) xs[i] = xp[i];
  __syncthreads();
  for (int o = threadIdx.x; o < 289; o += 256) {
    int oy = o / 17, ox = o - oy * 17;
    float acc = 0.f;
    for (int u = 0; u < 14; ++u) {
      const float* xr = &xs[(oy + u) * 30 + ox];
      const float* zr = &zs[u * 14];
#pragma unroll
      for (int v = 0; v < 14; ++v) acc = fmaf(zr[v], xr[v], acc);
    }
    out[bc * 289 + o] = acc;
  }
}

extern "C" void kernel_launch(void* const* d_in, const int* in_sizes, int n_in,
                              void* d_out, int out_size, void* d_ws, size_t ws_size,
                              hipStream_t stream) {
  const float* z = (const float*)d_in[0];
  const float* x = (const float*)d_in[1];
  const float* w_z = (const float*)d_in[2];
  const float* w_x = (const float*)d_in[3];
  const float* gamma_z = (const float*)d_in[4];
  const float* beta_z = (const float*)d_in[5];
  const float* mean_z = (const float*)d_in[6];
  const float* var_z = (const float*)d_in[7];
  const float* gamma_x = (const float*)d_in[8];
  const float* beta_x = (const float*)d_in[9];
  const float* mean_x = (const float*)d_in[10];
  const float* var_x = (const float*)d_in[11];

  char* ws = (char*)d_ws;
  f16* xb = (f16*)(ws + OFF_XB);
  f16* zb = (f16*)(ws + OFF_ZB);
  f16* wxA = (f16*)(ws + OFF_WX);
  f16* wzA = (f16*)(ws + OFF_WZ);
  float* bnx = (float*)(ws + OFF_BNX);
  float* bnz = (float*)(ws + OFF_BNZ);
  float* xf = (float*)(ws + OFF_XF);
  float* zf = (float*)(ws + OFF_ZF);
  float* out = (float*)d_out;

  nchw_to_nhwc_f16<32, 32><<<64 * 32 * 4, 256, 0, stream>>>(x, xb);
  nchw_to_nhwc_f16<16, 16><<<64 * 16 * 4, 256, 0, stream>>>(z, zb);
  prep_w<<<2304, 256, 0, stream>>>(w_x, wxA);
  prep_w<<<2304, 256, 0, stream>>>(w_z, wzA);
  prep_bn<<<1, 256, 0, stream>>>(gamma_x, beta_x, mean_x, var_x, bnx);
  prep_bn<<<1, 256, 0, stream>>>(gamma_z, beta_z, mean_z, var_z, bnz);

  // conv_x: N = 64*900 = 57600 -> 450 n-tiles; conv_z: N = 64*196 = 12544 -> 98 n-tiles
  conv_gemm<32, 32, 30, 30><<<dim3(450, 2), 256, 0, stream>>>(xb, wxA, bnx, xf);
  conv_gemm<16, 16, 14, 14><<<dim3(98, 2), 256, 0, stream>>>(zb, wzA, bnz, zf);

  xcorr_dw<<<64 * 256, 256, 0, stream>>>(zf, xf, out);
}